// Round 1
// baseline (169.657 us; speedup 1.0000x reference)
//
#include <hip/hip_runtime.h>

typedef __attribute__((ext_vector_type(8))) __bf16 bf16x8;
typedef __attribute__((ext_vector_type(4))) float f32x4;

namespace {
constexpr int S_LEN = 1024;
constexpr int D_HEAD = 64;
constexpr int DC = 128;            // combined head dim (x|y)
constexpr int QB = 64;             // q rows per block
constexpr int KB = 64;             // keys per k-tile
constexpr int NW = 4;              // waves per block
constexpr int NKSTEP = S_LEN / KB; // 16
constexpr long OUT2_OFF = 4L * 16 * 1024 * 64; // 4194304
constexpr float SCALE_LOG2E = 0.0625f * 1.44269504088896341f;
} // namespace

__device__ __forceinline__ unsigned short bf16u(float x) {
  unsigned u = __builtin_bit_cast(unsigned, x);
  return (unsigned short)((u + 0x7FFFu + ((u >> 16) & 1u)) >> 16); // RNE
}

// 16B-chunk XOR swizzle: element (r,c) of a [rows][cols] bf16 tile.
// chunk = (c>>3) ^ (r&7) keeps ds_read_b128 fragment reads conflict-free.
__device__ __forceinline__ int swz(int r, int c, int cols) {
  return r * cols + (((c >> 3) ^ (r & 7)) << 3) + (c & 7);
}

__global__ __launch_bounds__(256, 2) void fattn_kernel(
    const float* __restrict__ Qx, const float* __restrict__ Kx,
    const float* __restrict__ Vx, const float* __restrict__ Qy,
    const float* __restrict__ Ky, const float* __restrict__ Vy,
    float* __restrict__ out) {
  __shared__ unsigned short Kl[KB * DC];      // [key][dcomb] bf16, swizzled
  __shared__ unsigned short Vl[DC * KB];      // [dcomb][key] bf16, swizzled
  __shared__ unsigned short Pl[NW * 16 * KB]; // per-wave [q][key] bf16, swizzled

  const int tid = threadIdx.x;
  const int w   = tid >> 6;
  const int l   = tid & 63;
  const int l15 = l & 15;
  const int l4  = l >> 4;

  // head-contiguous per XCD: blocks 128b..128b+127 (8 heads) land on one XCD
  const int braw = blockIdx.x;
  const int bid  = (braw & 7) * 128 + (braw >> 3);
  const int bh   = bid >> 4; // 0..63
  const int qt   = bid & 15;
  const int q0   = qt * QB;

  const size_t hoff = (size_t)bh * S_LEN * D_HEAD;
  const float* qx = Qx + hoff; const float* qy = Qy + hoff;
  const float* kx = Kx + hoff; const float* ky = Ky + hoff;
  const float* vx = Vx + hoff; const float* vy = Vy + hoff;

  // ---- Q fragments (A-layout): row q = l15, d = 32*db + 8*l4 + i ----
  bf16x8 qf[4];
  {
    const int qrow = q0 + 16 * w + l15;
#pragma unroll
    for (int db = 0; db < 4; ++db) {
      const int dcomb = 32 * db + 8 * l4;
      const float* src = (dcomb < 64) ? (qx + qrow * D_HEAD + dcomb)
                                      : (qy + qrow * D_HEAD + (dcomb - 64));
      float4 a = *(const float4*)src;
      float4 c = *(const float4*)(src + 4);
      union { unsigned short s[8]; bf16x8 v; } u;
      u.s[0] = bf16u(a.x * SCALE_LOG2E); u.s[1] = bf16u(a.y * SCALE_LOG2E);
      u.s[2] = bf16u(a.z * SCALE_LOG2E); u.s[3] = bf16u(a.w * SCALE_LOG2E);
      u.s[4] = bf16u(c.x * SCALE_LOG2E); u.s[5] = bf16u(c.y * SCALE_LOG2E);
      u.s[6] = bf16u(c.z * SCALE_LOG2E); u.s[7] = bf16u(c.w * SCALE_LOG2E);
      qf[db] = u.v;
    }
  }

  f32x4 o[8];
#pragma unroll
  for (int i = 0; i < 8; ++i) o[i] = f32x4{0.f, 0.f, 0.f, 0.f};
  float m[4]    = {-__builtin_inff(), -__builtin_inff(), -__builtin_inff(), -__builtin_inff()};
  float lsum[4] = {0.f, 0.f, 0.f, 0.f};

  for (int k0 = 0; k0 < S_LEN; k0 += KB) {
    __syncthreads(); // previous tile fully consumed

    // ---- stage K: [key][dcomb] bf16; coalesced float4 loads, 8B LDS writes ----
#pragma unroll
    for (int j = 0; j < 8; ++j) {
      const int c   = tid + 256 * j; // 0..2047
      const int key = c >> 5;
      const int dc  = c & 31;        // float4 chunk within combined 128
      const float* src = (dc < 16) ? (kx + (size_t)(k0 + key) * D_HEAD + dc * 4)
                                   : (ky + (size_t)(k0 + key) * D_HEAD + (dc - 16) * 4);
      float4 v = *(const float4*)src;
      ushort4 pk;
      pk.x = bf16u(v.x); pk.y = bf16u(v.y); pk.z = bf16u(v.z); pk.w = bf16u(v.w);
      *(ushort4*)&Kl[swz(key, dc * 4, DC)] = pk;
    }

    // ---- stage V transposed: [dcomb][key] via in-register 4x4 quad transpose ----
#pragma unroll
    for (int j = 0; j < 8; ++j) {
      const int u  = w + NW * j; // 0..31: unit = 4 keys x 64 d of one stream
      const int st = u >> 4;     // stream: 0=Vx, 1=Vy
      const int kb = u & 15;     // 4-key block
      const int e  = l & 3;
      const int a  = l >> 2;     // d-chunk 0..15
      const float* vsrc = st ? vy : vx;
      float4 val = *(const float4*)(vsrc + (size_t)(k0 + kb * 4 + e) * D_HEAD + a * 4);
      float t0[4] = {val.x, val.y, val.z, val.w}; // t0[mi] = V[4kb+e][4a+mi]
      float t1[4], t2[4];
#pragma unroll
      for (int mi = 0; mi < 4; ++mi) {
        float other = __shfl_xor(t0[mi ^ 1], 1);
        t1[mi] = ((mi & 1) == (e & 1)) ? t0[mi] : other;
      }
#pragma unroll
      for (int mi = 0; mi < 4; ++mi) {
        float other = __shfl_xor(t1[mi ^ 2], 2);
        t2[mi] = ((mi & 2) == (e & 2)) ? t1[mi] : other;
      }
      // t2[mi] = V[4kb+mi][4a+e]
      const int dcomb = st * 64 + a * 4 + e;
      ushort4 pk;
      pk.x = bf16u(t2[0]); pk.y = bf16u(t2[1]); pk.z = bf16u(t2[2]); pk.w = bf16u(t2[3]);
      *(ushort4*)&Vl[swz(dcomb, kb * 4, KB)] = pk;
    }

    __syncthreads(); // tile visible to all waves

    // ---- QK^T: S-tile rows q=4*l4+r, cols key=16*kt+l15 ----
    f32x4 s[4];
#pragma unroll
    for (int kt = 0; kt < 4; ++kt) {
      f32x4 acc = f32x4{0.f, 0.f, 0.f, 0.f};
#pragma unroll
      for (int db = 0; db < 4; ++db) {
        bf16x8 bk = *(const bf16x8*)&Kl[swz(16 * kt + l15, 32 * db + 8 * l4, DC)];
        acc = __builtin_amdgcn_mfma_f32_16x16x32_bf16(qf[db], bk, acc, 0, 0, 0);
      }
      s[kt] = acc;
    }

    // ---- online softmax (log2-domain; Q pre-scaled by scale*log2e) ----
    unsigned short pout[4][4]; // [kt][r]
    float scl[4];
#pragma unroll
    for (int r = 0; r < 4; ++r) {
      float mx = fmaxf(fmaxf(s[0][r], s[1][r]), fmaxf(s[2][r], s[3][r]));
      mx = fmaxf(mx, __shfl_xor(mx, 1));
      mx = fmaxf(mx, __shfl_xor(mx, 2));
      mx = fmaxf(mx, __shfl_xor(mx, 4));
      mx = fmaxf(mx, __shfl_xor(mx, 8));
      const float mnew = fmaxf(m[r], mx);
      const float sc   = exp2f(m[r] - mnew);
      m[r] = mnew;
      scl[r] = sc;
      lsum[r] *= sc;
      float rs = 0.f;
#pragma unroll
      for (int kt = 0; kt < 4; ++kt) {
        float p = exp2f(s[kt][r] - mnew);
        rs += p;
        pout[kt][r] = bf16u(p);
      }
      rs += __shfl_xor(rs, 1);
      rs += __shfl_xor(rs, 2);
      rs += __shfl_xor(rs, 4);
      rs += __shfl_xor(rs, 8);
      lsum[r] += rs;
    }
#pragma unroll
    for (int dt = 0; dt < 8; ++dt)
#pragma unroll
      for (int r = 0; r < 4; ++r) o[dt][r] *= scl[r];

    // ---- P: D-layout regs -> per-wave LDS -> A-layout frags ----
    unsigned short* pw = &Pl[w * 16 * KB];
#pragma unroll
    for (int kt = 0; kt < 4; ++kt)
#pragma unroll
      for (int r = 0; r < 4; ++r)
        pw[swz(4 * l4 + r, 16 * kt + l15, KB)] = pout[kt][r];

    // ---- PV: o[dt] += P[16x32] * V[32x16] ----
#pragma unroll
    for (int sl = 0; sl < 2; ++sl) {
      bf16x8 pf = *(const bf16x8*)&pw[swz(l15, 32 * sl + 8 * l4, KB)];
#pragma unroll
      for (int dt = 0; dt < 8; ++dt) {
        bf16x8 vf = *(const bf16x8*)&Vl[swz(16 * dt + l15, 32 * sl + 8 * l4, KB)];
        o[dt] = __builtin_amdgcn_mfma_f32_16x16x32_bf16(pf, vf, o[dt], 0, 0, 0);
      }
    }
  }

  // ---- epilogue: normalize and store (rows 4*l4+r, col dcomb=16*dt+l15) ----
#pragma unroll
  for (int r = 0; r < 4; ++r) {
    const float inv  = 1.0f / lsum[r];
    const int   qrow = q0 + 16 * w + 4 * l4 + r;
#pragma unroll
    for (int dt = 0; dt < 8; ++dt) {
      const int dcomb = 16 * dt + l15;
      const float val = o[dt][r] * inv;
      if (dcomb < 64)
        out[hoff + (size_t)qrow * D_HEAD + dcomb] = val;
      else
        out[OUT2_OFF + hoff + (size_t)qrow * D_HEAD + (dcomb - 64)] = val;
    }
  }
}

extern "C" void kernel_launch(void* const* d_in, const int* in_sizes, int n_in,
                              void* d_out, int out_size, void* d_ws, size_t ws_size,
                              hipStream_t stream) {
  const float* Qx = (const float*)d_in[0];
  const float* Kx = (const float*)d_in[1];
  const float* Vx = (const float*)d_in[2];
  const float* Qy = (const float*)d_in[3];
  const float* Ky = (const float*)d_in[4];
  const float* Vy = (const float*)d_in[5];
  float* out = (float*)d_out;

  dim3 grid(64 * (S_LEN / QB)); // 1024 blocks
  dim3 block(256);
  fattn_kernel<<<grid, block, 0, stream>>>(Qx, Kx, Vx, Qy, Ky, Vy, out);
}

// Round 2
// 83.274 us; speedup vs baseline: 2.0373x; 2.0373x over previous
//
#include <hip/hip_runtime.h>

typedef __attribute__((ext_vector_type(8))) __bf16 bf16x8;
typedef __attribute__((ext_vector_type(4))) float f32x4;
typedef __attribute__((ext_vector_type(16))) float f32x16;

namespace {
constexpr int S_LEN = 1024;
constexpr int D_HEAD = 64;
constexpr int DC = 128;            // combined head dim (x|y)
constexpr int KB = 64;             // keys per k-tile
constexpr int NT = 16;             // k-tiles
constexpr int TILE_B = 16384;      // bytes per staged (64x128 bf16) tile
constexpr long OUT2_OFF = 4L * 16 * 1024 * 64; // 4194304
constexpr float SCALE_LOG2E = 0.0625f * 1.44269504088896341f;
constexpr size_t KWS = 64UL * NT * TILE_B;     // 16 MiB per tensor image
} // namespace

__device__ __forceinline__ unsigned short bf16u(float x) {
  unsigned u = __builtin_bit_cast(unsigned, x);
  return (unsigned short)((u + 0x7FFFu + ((u >> 16) & 1u)) >> 16); // RNE
}

// ---- swizzled tile byte offsets (16-slot XOR; 2-way max bank aliasing) ----
// K tile: [key 0..63][dc 0..127] bf16
__device__ __forceinline__ int koff(int key, int dc) {
  return key * 256 + ((((dc >> 3) ^ (key & 15)) & 15) << 4) + ((dc & 7) << 1);
}
// V tile (transposed): element (key, dc) stored at row r=dc>>1, col c=(dc&1)*64+key
__device__ __forceinline__ int voff(int dc, int key) {
  int r = dc >> 1, c = ((dc & 1) << 6) + key;
  return r * 256 + ((((c >> 3) ^ (r & 15)) & 15) << 4) + ((c & 7) << 1);
}

// =====================  pre-pass: fp32 -> bf16 swizzled images  =====================
__global__ __launch_bounds__(256) void prepass_kernel(
    const float* __restrict__ Kx, const float* __restrict__ Ky,
    const float* __restrict__ Vx, const float* __restrict__ Vy,
    unsigned char* __restrict__ kb, unsigned char* __restrict__ vb) {
  const int c = blockIdx.x * 256 + threadIdx.x; // 0 .. 2M-1
  const bool isV = c >= (1 << 20);
  const int cc = c & ((1 << 20) - 1);
  const int head = cc >> 14;          // 16384 chunks per head
  const int rem = cc & 16383;
  const int tile = rem >> 10;         // 1024 chunks per tile
  const int within = rem & 1023;
  const int r = within >> 4;          // dest row 0..63
  const int p = within & 15;          // dest 16B slot
  const int cchunk = p ^ (r & 15);    // source col-chunk
  const size_t hbase = (size_t)head * (S_LEN * D_HEAD);

  union { unsigned short s[8]; uint4 q; } u;
  if (!isV) {
    const int key = tile * 64 + r;
    const int dc0 = cchunk * 8;
    const float* src = (dc0 < 64) ? (Kx + hbase + (size_t)key * 64 + dc0)
                                  : (Ky + hbase + (size_t)key * 64 + (dc0 - 64));
    float4 a = *(const float4*)src;
    float4 b = *(const float4*)(src + 4);
    u.s[0] = bf16u(a.x); u.s[1] = bf16u(a.y); u.s[2] = bf16u(a.z); u.s[3] = bf16u(a.w);
    u.s[4] = bf16u(b.x); u.s[5] = bf16u(b.y); u.s[6] = bf16u(b.z); u.s[7] = bf16u(b.w);
    *(uint4*)(kb + (size_t)cc * 16) = u.q;
  } else {
    const int dc = 2 * r + (cchunk >> 3);
    const int key0 = (cchunk & 7) * 8;
    const float* src = (dc < 64) ? (Vx + hbase + dc) : (Vy + hbase + (dc - 64));
#pragma unroll
    for (int j = 0; j < 8; ++j)
      u.s[j] = bf16u(src[(size_t)(tile * 64 + key0 + j) * 64]);
    *(uint4*)(vb + (size_t)cc * 16) = u.q;
  }
}

// =====================  main flash-attention kernel  =====================
__global__ __launch_bounds__(512, 2) void fattn2_kernel(
    const float* __restrict__ Qx, const float* __restrict__ Qy,
    const unsigned char* __restrict__ kb, const unsigned char* __restrict__ vb,
    float* __restrict__ out) {
  __shared__ __align__(16) unsigned char s_k[2][TILE_B];
  __shared__ __align__(16) unsigned char s_v[2][TILE_B];
  __shared__ float s_b[8][32];

  const int tid = threadIdx.x;
  const int w = tid >> 6;      // wave 0..7
  const int l = tid & 63;
  const int q32 = l & 31;
  const int h = l >> 5;

  // XCD-contiguous remap: XCD x gets heads 8x..8x+7 (32 blocks each)
  const int braw = blockIdx.x;
  const int j = braw >> 3;
  const int bh = 8 * (braw & 7) + (j >> 2); // 0..63
  const int qt = j & 3;
  const int q0 = qt * 256 + w * 32;

  const size_t hoff = (size_t)bh * (S_LEN * D_HEAD);
  const unsigned char* kbh = kb + (size_t)bh * (NT * TILE_B);
  const unsigned char* vbh = vb + (size_t)bh * (NT * TILE_B);

  auto stage = [&](int buf, int t) {
#pragma unroll
    for (int ps = 0; ps < 2; ++ps) {
      const int off = w * 1024 + ps * 8192;
      __builtin_amdgcn_global_load_lds(
          (const __attribute__((address_space(1))) unsigned int*)(const void*)(kbh + (size_t)t * TILE_B + off + l * 16),
          (__attribute__((address_space(3))) unsigned int*)(void*)(&s_k[buf][off]),
          16, 0, 0);
      __builtin_amdgcn_global_load_lds(
          (const __attribute__((address_space(1))) unsigned int*)(const void*)(vbh + (size_t)t * TILE_B + off + l * 16),
          (__attribute__((address_space(3))) unsigned int*)(void*)(&s_v[buf][off]),
          16, 0, 0);
    }
  };

  stage(0, 0); // tile 0 in flight while we build Q fragments

  // Q fragments (B-operand of swapped QK^T): lane holds Q[q0+q32][16*sp + 8h + i]
  bf16x8 qf[8];
  {
    const int qrow = q0 + q32;
#pragma unroll
    for (int sp = 0; sp < 8; ++sp) {
      const int dc0 = 16 * sp + 8 * h;
      const float* src = (dc0 < 64) ? (Qx + hoff + (size_t)qrow * 64 + dc0)
                                    : (Qy + hoff + (size_t)qrow * 64 + (dc0 - 64));
      float4 a = *(const float4*)src;
      float4 b = *(const float4*)(src + 4);
      union { unsigned short s[8]; bf16x8 v; } u;
      u.s[0] = bf16u(a.x * SCALE_LOG2E); u.s[1] = bf16u(a.y * SCALE_LOG2E);
      u.s[2] = bf16u(a.z * SCALE_LOG2E); u.s[3] = bf16u(a.w * SCALE_LOG2E);
      u.s[4] = bf16u(b.x * SCALE_LOG2E); u.s[5] = bf16u(b.y * SCALE_LOG2E);
      u.s[6] = bf16u(b.z * SCALE_LOG2E); u.s[7] = bf16u(b.w * SCALE_LOG2E);
      qf[sp] = u.v;
    }
  }

  f32x16 o[4] = {};
  float m = -__builtin_inff();
  float lsum = 0.f;

  __syncthreads(); // tile 0 resident

  int cur = 0;
  for (int t = 0; t < NT; ++t) {
    if (t + 1 < NT) stage(cur ^ 1, t + 1);

    // ---- QK^T (swapped): St[key][q], keys 0..31 -> st0, 32..63 -> st1 ----
    f32x16 st0 = {}, st1 = {};
    __builtin_amdgcn_s_setprio(1);
#pragma unroll
    for (int sp = 0; sp < 8; ++sp) {
      const int dc0 = 16 * sp + 8 * h;
      bf16x8 k0 = *(const bf16x8*)&s_k[cur][koff(q32, dc0)];
      bf16x8 k1 = *(const bf16x8*)&s_k[cur][koff(32 + q32, dc0)];
      st0 = __builtin_amdgcn_mfma_f32_32x32x16_bf16(k0, qf[sp], st0, 0, 0, 0);
      st1 = __builtin_amdgcn_mfma_f32_32x32x16_bf16(k1, qf[sp], st1, 0, 0, 0);
    }
    __builtin_amdgcn_s_setprio(0);

    // ---- online softmax, fully in-register (q = q32 is lane-local) ----
    float mx = st0[0];
#pragma unroll
    for (int r = 1; r < 16; ++r) mx = fmaxf(mx, st0[r]);
#pragma unroll
    for (int r = 0; r < 16; ++r) mx = fmaxf(mx, st1[r]);
    mx = fmaxf(mx, __shfl_xor(mx, 32));

    const bool skip = (mx <= m + 8.0f); // T13 defer-max (log2 domain)
    if (!__all(skip)) {
      const float mnew = fmaxf(m, mx);
      const float scl = exp2f(m - mnew);
      m = mnew;
      lsum *= scl;
      if (l < 32) s_b[w][l] = scl;
      float sf[4][4];
#pragma unroll
      for (int g = 0; g < 4; ++g) {
        float4 v = *(const float4*)&s_b[w][8 * g + 4 * h];
        sf[g][0] = v.x; sf[g][1] = v.y; sf[g][2] = v.z; sf[g][3] = v.w;
      }
#pragma unroll
      for (int nt2 = 0; nt2 < 4; ++nt2)
#pragma unroll
        for (int r = 0; r < 16; ++r) o[nt2][r] *= sf[r >> 2][r & 3];
    }

    // ---- P = exp2(St - m), row-sum, pack to bf16 pairs ----
    float rs = 0.f;
    unsigned pk[2][8];
#pragma unroll
    for (int jj = 0; jj < 8; ++jj) {
      float p0 = exp2f(st0[2 * jj] - m);
      float p1 = exp2f(st0[2 * jj + 1] - m);
      rs += p0 + p1;
      union { unsigned u; __bf16 e[2]; } cu;
      cu.e[0] = (__bf16)p0; cu.e[1] = (__bf16)p1;
      pk[0][jj] = cu.u;
    }
#pragma unroll
    for (int jj = 0; jj < 8; ++jj) {
      float p0 = exp2f(st1[2 * jj] - m);
      float p1 = exp2f(st1[2 * jj + 1] - m);
      rs += p0 + p1;
      union { unsigned u; __bf16 e[2]; } cu;
      cu.e[0] = (__bf16)p0; cu.e[1] = (__bf16)p1;
      pk[1][jj] = cu.u;
    }
    rs += __shfl_xor(rs, 32);
    lsum += rs;

    // ---- P -> PV A-fragments: half-exchange via shfl_xor(32) ----
    bf16x8 af[4];
#pragma unroll
    for (int ks = 0; ks < 4; ++ks) {
      const int mt = ks >> 1, i0 = 4 * (ks & 1);
      unsigned ow0 = h ? pk[mt][i0 + 0] : pk[mt][i0 + 2];
      unsigned ow1 = h ? pk[mt][i0 + 1] : pk[mt][i0 + 3];
      unsigned e0 = (unsigned)__shfl_xor((int)ow0, 32);
      unsigned e1 = (unsigned)__shfl_xor((int)ow1, 32);
      union { unsigned u[4]; bf16x8 v; } fu;
      fu.u[0] = h ? e0 : pk[mt][i0 + 0];
      fu.u[1] = h ? e1 : pk[mt][i0 + 1];
      fu.u[2] = h ? pk[mt][i0 + 2] : e0;
      fu.u[3] = h ? pk[mt][i0 + 3] : e1;
      af[ks] = fu.v;
    }

    // ---- PV: o[nt] += P(32q x 16k) * V(16k x 32dc) ----
    __builtin_amdgcn_s_setprio(1);
#pragma unroll
    for (int ks = 0; ks < 4; ++ks) {
      const int key0 = 16 * ks + 8 * h;
#pragma unroll
      for (int nt2 = 0; nt2 < 4; ++nt2) {
        bf16x8 vf = *(const bf16x8*)&s_v[cur][voff(32 * nt2 + q32, key0)];
        o[nt2] = __builtin_amdgcn_mfma_f32_32x32x16_bf16(af[ks], vf, o[nt2], 0, 0, 0);
      }
    }
    __builtin_amdgcn_s_setprio(0);

    __syncthreads(); // staged tile complete (vmcnt 0) + all reads of cur done
    cur ^= 1;
  }

  // ---- epilogue: normalize (1/lsum broadcast via LDS) and store ----
  {
    const float inv = 1.0f / lsum;
    if (l < 32) s_b[w][l] = inv;
    float sf[4][4];
#pragma unroll
    for (int g = 0; g < 4; ++g) {
      float4 v = *(const float4*)&s_b[w][8 * g + 4 * h];
      sf[g][0] = v.x; sf[g][1] = v.y; sf[g][2] = v.z; sf[g][3] = v.w;
    }
#pragma unroll
    for (int nt2 = 0; nt2 < 4; ++nt2) {
      const int dc = 32 * nt2 + q32;
#pragma unroll
      for (int r = 0; r < 16; ++r) {
        const int q = (r & 3) + 8 * (r >> 2) + 4 * h;
        const float val = o[nt2][r] * sf[r >> 2][r & 3];
        const size_t row = hoff + (size_t)(q0 + q) * 64;
        if (dc < 64) out[row + dc] = val;
        else out[OUT2_OFF + row + (dc - 64)] = val;
      }
    }
  }
}

// =====================  fallback (round-1, verified) for small ws  =====================
__device__ __forceinline__ int swz(int r, int c, int cols) {
  return r * cols + (((c >> 3) ^ (r & 7)) << 3) + (c & 7);
}

__global__ __launch_bounds__(256, 2) void fattn_fb_kernel(
    const float* __restrict__ Qx, const float* __restrict__ Kx,
    const float* __restrict__ Vx, const float* __restrict__ Qy,
    const float* __restrict__ Ky, const float* __restrict__ Vy,
    float* __restrict__ out) {
  __shared__ unsigned short Kl[KB * DC];
  __shared__ unsigned short Vl[DC * KB];
  __shared__ unsigned short Pl[4 * 16 * KB];

  const int tid = threadIdx.x;
  const int w = tid >> 6, l = tid & 63, l15 = l & 15, l4 = l >> 4;
  const int braw = blockIdx.x;
  const int bid = (braw & 7) * 128 + (braw >> 3);
  const int bh = bid >> 4, qt = bid & 15, q0 = qt * 64;
  const size_t hoff = (size_t)bh * S_LEN * D_HEAD;
  const float* qx = Qx + hoff; const float* qy = Qy + hoff;
  const float* kx = Kx + hoff; const float* ky = Ky + hoff;
  const float* vx = Vx + hoff; const float* vy = Vy + hoff;

  bf16x8 qf[4];
  {
    const int qrow = q0 + 16 * w + l15;
#pragma unroll
    for (int db = 0; db < 4; ++db) {
      const int dcomb = 32 * db + 8 * l4;
      const float* src = (dcomb < 64) ? (qx + qrow * D_HEAD + dcomb)
                                      : (qy + qrow * D_HEAD + (dcomb - 64));
      float4 a = *(const float4*)src;
      float4 c = *(const float4*)(src + 4);
      union { unsigned short s[8]; bf16x8 v; } u;
      u.s[0] = bf16u(a.x * SCALE_LOG2E); u.s[1] = bf16u(a.y * SCALE_LOG2E);
      u.s[2] = bf16u(a.z * SCALE_LOG2E); u.s[3] = bf16u(a.w * SCALE_LOG2E);
      u.s[4] = bf16u(c.x * SCALE_LOG2E); u.s[5] = bf16u(c.y * SCALE_LOG2E);
      u.s[6] = bf16u(c.z * SCALE_LOG2E); u.s[7] = bf16u(c.w * SCALE_LOG2E);
      qf[db] = u.v;
    }
  }

  f32x4 o[8];
#pragma unroll
  for (int i = 0; i < 8; ++i) o[i] = f32x4{0.f, 0.f, 0.f, 0.f};
  float m[4] = {-__builtin_inff(), -__builtin_inff(), -__builtin_inff(), -__builtin_inff()};
  float lsum[4] = {0.f, 0.f, 0.f, 0.f};

  for (int k0 = 0; k0 < S_LEN; k0 += KB) {
    __syncthreads();
#pragma unroll
    for (int jj = 0; jj < 8; ++jj) {
      const int c = tid + 256 * jj;
      const int key = c >> 5, dc = c & 31;
      const float* src = (dc < 16) ? (kx + (size_t)(k0 + key) * D_HEAD + dc * 4)
                                   : (ky + (size_t)(k0 + key) * D_HEAD + (dc - 16) * 4);
      float4 v = *(const float4*)src;
      ushort4 pkk;
      pkk.x = bf16u(v.x); pkk.y = bf16u(v.y); pkk.z = bf16u(v.z); pkk.w = bf16u(v.w);
      *(ushort4*)&Kl[swz(key, dc * 4, DC)] = pkk;
    }
#pragma unroll
    for (int jj = 0; jj < 8; ++jj) {
      const int u = w + 4 * jj, st = u >> 4, kbb = u & 15;
      const int e = l & 3, a = l >> 2;
      const float* vsrc = st ? vy : vx;
      float4 val = *(const float4*)(vsrc + (size_t)(k0 + kbb * 4 + e) * D_HEAD + a * 4);
      float t0[4] = {val.x, val.y, val.z, val.w};
      float t1[4], t2[4];
#pragma unroll
      for (int mi = 0; mi < 4; ++mi) {
        float other = __shfl_xor(t0[mi ^ 1], 1);
        t1[mi] = ((mi & 1) == (e & 1)) ? t0[mi] : other;
      }
#pragma unroll
      for (int mi = 0; mi < 4; ++mi) {
        float other = __shfl_xor(t1[mi ^ 2], 2);
        t2[mi] = ((mi & 2) == (e & 2)) ? t1[mi] : other;
      }
      const int dcomb = st * 64 + a * 4 + e;
      ushort4 pkk;
      pkk.x = bf16u(t2[0]); pkk.y = bf16u(t2[1]); pkk.z = bf16u(t2[2]); pkk.w = bf16u(t2[3]);
      *(ushort4*)&Vl[swz(dcomb, kbb * 4, KB)] = pkk;
    }
    __syncthreads();

    f32x4 s[4];
#pragma unroll
    for (int kt = 0; kt < 4; ++kt) {
      f32x4 acc = f32x4{0.f, 0.f, 0.f, 0.f};
#pragma unroll
      for (int db = 0; db < 4; ++db) {
        bf16x8 bk = *(const bf16x8*)&Kl[swz(16 * kt + l15, 32 * db + 8 * l4, DC)];
        acc = __builtin_amdgcn_mfma_f32_16x16x32_bf16(qf[db], bk, acc, 0, 0, 0);
      }
      s[kt] = acc;
    }

    unsigned short pout[4][4];
    float scl[4];
#pragma unroll
    for (int r = 0; r < 4; ++r) {
      float mxx = fmaxf(fmaxf(s[0][r], s[1][r]), fmaxf(s[2][r], s[3][r]));
      mxx = fmaxf(mxx, __shfl_xor(mxx, 1));
      mxx = fmaxf(mxx, __shfl_xor(mxx, 2));
      mxx = fmaxf(mxx, __shfl_xor(mxx, 4));
      mxx = fmaxf(mxx, __shfl_xor(mxx, 8));
      const float mnew = fmaxf(m[r], mxx);
      const float sc = exp2f(m[r] - mnew);
      m[r] = mnew; scl[r] = sc; lsum[r] *= sc;
      float rsum = 0.f;
#pragma unroll
      for (int kt = 0; kt < 4; ++kt) {
        float p = exp2f(s[kt][r] - mnew);
        rsum += p;
        pout[kt][r] = bf16u(p);
      }
      rsum += __shfl_xor(rsum, 1);
      rsum += __shfl_xor(rsum, 2);
      rsum += __shfl_xor(rsum, 4);
      rsum += __shfl_xor(rsum, 8);
      lsum[r] += rsum;
    }
#pragma unroll
    for (int dt = 0; dt < 8; ++dt)
#pragma unroll
      for (int r = 0; r < 4; ++r) o[dt][r] *= scl[r];

    unsigned short* pw = &Pl[w * 16 * KB];
#pragma unroll
    for (int kt = 0; kt < 4; ++kt)
#pragma unroll
      for (int r = 0; r < 4; ++r)
        pw[swz(4 * l4 + r, 16 * kt + l15, KB)] = pout[kt][r];

#pragma unroll
    for (int sl = 0; sl < 2; ++sl) {
      bf16x8 pf = *(const bf16x8*)&pw[swz(l15, 32 * sl + 8 * l4, KB)];
#pragma unroll
      for (int dt = 0; dt < 8; ++dt) {
        bf16x8 vf = *(const bf16x8*)&Vl[swz(16 * dt + l15, 32 * sl + 8 * l4, KB)];
        o[dt] = __builtin_amdgcn_mfma_f32_16x16x32_bf16(pf, vf, o[dt], 0, 0, 0);
      }
    }
  }

#pragma unroll
  for (int r = 0; r < 4; ++r) {
    const float inv = 1.0f / lsum[r];
    const int qrow = q0 + 16 * w + 4 * l4 + r;
#pragma unroll
    for (int dt = 0; dt < 8; ++dt) {
      const int dcomb = 16 * dt + l15;
      const float val = o[dt][r] * inv;
      if (dcomb < 64) out[hoff + (size_t)qrow * D_HEAD + dcomb] = val;
      else out[OUT2_OFF + hoff + (size_t)qrow * D_HEAD + (dcomb - 64)] = val;
    }
  }
}

extern "C" void kernel_launch(void* const* d_in, const int* in_sizes, int n_in,
                              void* d_out, int out_size, void* d_ws, size_t ws_size,
                              hipStream_t stream) {
  const float* Qx = (const float*)d_in[0];
  const float* Kx = (const float*)d_in[1];
  const float* Vx = (const float*)d_in[2];
  const float* Qy = (const float*)d_in[3];
  const float* Ky = (const float*)d_in[4];
  const float* Vy = (const float*)d_in[5];
  float* out = (float*)d_out;

  if (ws_size >= 2 * KWS) {
    unsigned char* kbp = (unsigned char*)d_ws;
    unsigned char* vbp = kbp + KWS;
    prepass_kernel<<<8192, 256, 0, stream>>>(Kx, Ky, Vx, Vy, kbp, vbp);
    fattn2_kernel<<<256, 512, 0, stream>>>(Qx, Qy, kbp, vbp, out);
  } else {
    fattn_fb_kernel<<<1024, 256, 0, stream>>>(Qx, Kx, Vx, Qy, Ky, Vy, out);
  }
}

// Round 3
// 77.272 us; speedup vs baseline: 2.1956x; 1.0777x over previous
//
#include <hip/hip_runtime.h>

typedef __attribute__((ext_vector_type(8))) __bf16 bf16x8;
typedef __attribute__((ext_vector_type(4))) float f32x4;
typedef __attribute__((ext_vector_type(16))) float f32x16;

namespace {
constexpr int S_LEN = 1024;
constexpr int D_HEAD = 64;
constexpr int DC = 128;            // combined head dim (x|y)
constexpr int KB = 64;             // keys per k-tile
constexpr int NT = 16;             // k-tiles
constexpr int TILE_B = 16384;      // bytes per staged (64x128 bf16) tile
constexpr long OUT2_OFF = 4L * 16 * 1024 * 64; // 4194304
constexpr float SCALE_LOG2E = 0.0625f * 1.44269504088896341f;
constexpr size_t KWS = 64UL * NT * TILE_B;     // 16 MiB per tensor image
} // namespace

__device__ __forceinline__ unsigned short bf16u(float x) {
  unsigned u = __builtin_bit_cast(unsigned, x);
  return (unsigned short)((u + 0x7FFFu + ((u >> 16) & 1u)) >> 16); // RNE
}

// =====================  pre-pass: fp32 -> bf16 fragment-plane images  ==========
// K image tile (16 KB): byte = hh*8192 + sp*1024 + l*16 holds
//   K[tile*64 + hh*32 + (l&31)][16*sp + 8*(l>>5) + 0..7]
// V image tile (16 KB): byte = (ks*4+nt2)*1024 + l*16 holds
//   V^T: keys tile*64 + 16*ks + 8*(l>>5) + 0..7 at dc = 32*nt2 + (l&31)
__global__ __launch_bounds__(256) void prepass_kernel(
    const float* __restrict__ Kx, const float* __restrict__ Ky,
    const float* __restrict__ Vx, const float* __restrict__ Vy,
    unsigned char* __restrict__ kb, unsigned char* __restrict__ vb) {
  const int c = blockIdx.x * 256 + threadIdx.x; // 0 .. 2M-1
  const bool isV = c >= (1 << 20);
  const int cc = c & ((1 << 20) - 1);
  const int head = cc >> 14;
  const int tile = (cc >> 10) & 15;
  const int within = cc & 1023;
  const int plane = within >> 6;
  const int l = within & 63;
  const int l31 = l & 31, h = l >> 5;
  const size_t hbase = (size_t)head * (S_LEN * D_HEAD);

  union { unsigned short s[8]; uint4 q; } u;
  if (!isV) {
    const int hh = plane >> 3, sp = plane & 7;
    const int key = tile * 64 + hh * 32 + l31;
    const int dc0 = sp * 16 + h * 8;
    const float* src = (dc0 < 64) ? (Kx + hbase + (size_t)key * 64 + dc0)
                                  : (Ky + hbase + (size_t)key * 64 + (dc0 - 64));
    float4 a = *(const float4*)src;
    float4 b = *(const float4*)(src + 4);
    u.s[0] = bf16u(a.x); u.s[1] = bf16u(a.y); u.s[2] = bf16u(a.z); u.s[3] = bf16u(a.w);
    u.s[4] = bf16u(b.x); u.s[5] = bf16u(b.y); u.s[6] = bf16u(b.z); u.s[7] = bf16u(b.w);
    *(uint4*)(kb + (size_t)cc * 16) = u.q;
  } else {
    const int ks = plane >> 2, nt2 = plane & 3;
    const int dc = nt2 * 32 + l31;
    const int key0 = tile * 64 + ks * 16 + h * 8;
    const float* src = (dc < 64) ? (Vx + hbase + dc) : (Vy + hbase + (dc - 64));
#pragma unroll
    for (int j = 0; j < 8; ++j)
      u.s[j] = bf16u(src[(size_t)(key0 + j) * 64]);
    *(uint4*)(vb + (size_t)cc * 16) = u.q;
  }
}

// =====================  main flash-attention kernel  =====================
__global__ __launch_bounds__(256, 2) void fattn2_kernel(
    const float* __restrict__ Qx, const float* __restrict__ Qy,
    const unsigned char* __restrict__ kb, const unsigned char* __restrict__ vb,
    float* __restrict__ out) {
  __shared__ __align__(16) unsigned char s_k[2][TILE_B];
  __shared__ __align__(16) unsigned char s_v[2][TILE_B];
  __shared__ float s_b[4][32];

  const int tid = threadIdx.x;
  const int w = tid >> 6;      // wave 0..3
  const int l = tid & 63;
  const int q32 = l & 31;
  const int h = l >> 5;

  // XCD-contiguous remap: XCD x gets heads 8x..8x+7 (64 blocks each)
  const int braw = blockIdx.x;
  const int j = braw >> 3;                  // 0..63
  const int bh = 8 * (braw & 7) + (j >> 3); // 0..63
  const int qt = j & 7;                     // 0..7
  const int q0 = qt * 128 + w * 32;

  const size_t hoff = (size_t)bh * (S_LEN * D_HEAD);
  const unsigned char* kbh = kb + (size_t)bh * (NT * TILE_B);
  const unsigned char* vbh = vb + (size_t)bh * (NT * TILE_B);

  auto stage = [&](int buf, int t) {
#pragma unroll
    for (int ps = 0; ps < 4; ++ps) {
      const int off = ps * 4096 + tid * 16;
      __builtin_amdgcn_global_load_lds(
          (const __attribute__((address_space(1))) unsigned int*)(const void*)(kbh + (size_t)t * TILE_B + off),
          (__attribute__((address_space(3))) unsigned int*)(void*)(&s_k[buf][off]),
          16, 0, 0);
      __builtin_amdgcn_global_load_lds(
          (const __attribute__((address_space(1))) unsigned int*)(const void*)(vbh + (size_t)t * TILE_B + off),
          (__attribute__((address_space(3))) unsigned int*)(void*)(&s_v[buf][off]),
          16, 0, 0);
    }
  };

  stage(0, 0); // tile 0 in flight while we build Q fragments

  // Q fragments (B-operand of swapped QK^T): lane holds Q[q0+q32][16*sp + 8h + i]
  bf16x8 qf[8];
  {
    const int qrow = q0 + q32;
#pragma unroll
    for (int sp = 0; sp < 8; ++sp) {
      const int dc0 = 16 * sp + 8 * h;
      const float* src = (dc0 < 64) ? (Qx + hoff + (size_t)qrow * 64 + dc0)
                                    : (Qy + hoff + (size_t)qrow * 64 + (dc0 - 64));
      float4 a = *(const float4*)src;
      float4 b = *(const float4*)(src + 4);
      union { unsigned short s[8]; bf16x8 v; } u;
      u.s[0] = bf16u(a.x * SCALE_LOG2E); u.s[1] = bf16u(a.y * SCALE_LOG2E);
      u.s[2] = bf16u(a.z * SCALE_LOG2E); u.s[3] = bf16u(a.w * SCALE_LOG2E);
      u.s[4] = bf16u(b.x * SCALE_LOG2E); u.s[5] = bf16u(b.y * SCALE_LOG2E);
      u.s[6] = bf16u(b.z * SCALE_LOG2E); u.s[7] = bf16u(b.w * SCALE_LOG2E);
      qf[sp] = u.v;
    }
  }

  f32x16 o[4] = {};
  float m = -__builtin_inff();
  float lsum = 0.f;

  __syncthreads(); // tile 0 resident

  int cur = 0;
  for (int t = 0; t < NT; ++t) {
    if (t + 1 < NT) stage(cur ^ 1, t + 1);

    // ---- QK^T (swapped): St[key][q]; A = K fragment-planes, B = Q regs ----
    const unsigned char* kbase = &s_k[cur][l * 16];
    f32x16 st0 = {}, st1 = {};
    __builtin_amdgcn_s_setprio(1);
#pragma unroll
    for (int sp = 0; sp < 8; ++sp) {
      bf16x8 k0 = *(const bf16x8*)(kbase + sp * 1024);
      bf16x8 k1 = *(const bf16x8*)(kbase + 8192 + sp * 1024);
      st0 = __builtin_amdgcn_mfma_f32_32x32x16_bf16(k0, qf[sp], st0, 0, 0, 0);
      st1 = __builtin_amdgcn_mfma_f32_32x32x16_bf16(k1, qf[sp], st1, 0, 0, 0);
    }
    __builtin_amdgcn_s_setprio(0);

    // ---- online softmax, fully in-register (q = q32 is lane-local) ----
    float mx = st0[0];
#pragma unroll
    for (int r = 1; r < 16; ++r) mx = fmaxf(mx, st0[r]);
#pragma unroll
    for (int r = 0; r < 16; ++r) mx = fmaxf(mx, st1[r]);
    mx = fmaxf(mx, __shfl_xor(mx, 32));

    const bool skip = (mx <= m + 8.0f); // T13 defer-max (log2 domain)
    if (!__all(skip)) {
      const float mnew = fmaxf(m, mx);
      const float scl = exp2f(m - mnew);
      m = mnew;
      lsum *= scl;
      if (l < 32) s_b[w][l] = scl;
      float sf[4][4];
#pragma unroll
      for (int g = 0; g < 4; ++g) {
        float4 v = *(const float4*)&s_b[w][8 * g + 4 * h];
        sf[g][0] = v.x; sf[g][1] = v.y; sf[g][2] = v.z; sf[g][3] = v.w;
      }
#pragma unroll
      for (int nt2 = 0; nt2 < 4; ++nt2)
#pragma unroll
        for (int r = 0; r < 16; ++r) o[nt2][r] *= sf[r >> 2][r & 3];
    }

    // ---- P = exp2(St - m), row-sum, pack to bf16 pairs ----
    float rs = 0.f;
    unsigned pk[2][8];
#pragma unroll
    for (int jj = 0; jj < 8; ++jj) {
      float p0 = exp2f(st0[2 * jj] - m);
      float p1 = exp2f(st0[2 * jj + 1] - m);
      rs += p0 + p1;
      union { unsigned u; __bf16 e[2]; } cu;
      cu.e[0] = (__bf16)p0; cu.e[1] = (__bf16)p1;
      pk[0][jj] = cu.u;
    }
#pragma unroll
    for (int jj = 0; jj < 8; ++jj) {
      float p0 = exp2f(st1[2 * jj] - m);
      float p1 = exp2f(st1[2 * jj + 1] - m);
      rs += p0 + p1;
      union { unsigned u; __bf16 e[2]; } cu;
      cu.e[0] = (__bf16)p0; cu.e[1] = (__bf16)p1;
      pk[1][jj] = cu.u;
    }
    rs += __shfl_xor(rs, 32);
    lsum += rs;

    // ---- P -> PV A-fragments: half-exchange via shfl_xor(32) ----
    bf16x8 af[4];
#pragma unroll
    for (int ks = 0; ks < 4; ++ks) {
      const int mt = ks >> 1, i0 = 4 * (ks & 1);
      unsigned ow0 = h ? pk[mt][i0 + 0] : pk[mt][i0 + 2];
      unsigned ow1 = h ? pk[mt][i0 + 1] : pk[mt][i0 + 3];
      unsigned e0 = (unsigned)__shfl_xor((int)ow0, 32);
      unsigned e1 = (unsigned)__shfl_xor((int)ow1, 32);
      union { unsigned u[4]; bf16x8 v; } fu;
      fu.u[0] = h ? e0 : pk[mt][i0 + 0];
      fu.u[1] = h ? e1 : pk[mt][i0 + 1];
      fu.u[2] = h ? pk[mt][i0 + 2] : e0;
      fu.u[3] = h ? pk[mt][i0 + 3] : e1;
      af[ks] = fu.v;
    }

    // ---- PV: o[nt2] += P(32q x 16k) * V(16k x 32dc); V fragment-planes ----
    const unsigned char* vbase = &s_v[cur][l * 16];
    __builtin_amdgcn_s_setprio(1);
#pragma unroll
    for (int ks = 0; ks < 4; ++ks) {
#pragma unroll
      for (int nt2 = 0; nt2 < 4; ++nt2) {
        bf16x8 vf = *(const bf16x8*)(vbase + (ks * 4 + nt2) * 1024);
        o[nt2] = __builtin_amdgcn_mfma_f32_32x32x16_bf16(af[ks], vf, o[nt2], 0, 0, 0);
      }
    }
    __builtin_amdgcn_s_setprio(0);

    __syncthreads(); // staged tile complete + all reads of cur done
    cur ^= 1;
  }

  // ---- epilogue: normalize (1/lsum broadcast via LDS) and store ----
  {
    const float inv = 1.0f / lsum;
    if (l < 32) s_b[w][l] = inv;
    float sf[4][4];
#pragma unroll
    for (int g = 0; g < 4; ++g) {
      float4 v = *(const float4*)&s_b[w][8 * g + 4 * h];
      sf[g][0] = v.x; sf[g][1] = v.y; sf[g][2] = v.z; sf[g][3] = v.w;
    }
#pragma unroll
    for (int nt2 = 0; nt2 < 4; ++nt2) {
      const int dc = 32 * nt2 + q32;
#pragma unroll
      for (int r = 0; r < 16; ++r) {
        const int q = (r & 3) + 8 * (r >> 2) + 4 * h;
        const float val = o[nt2][r] * sf[r >> 2][r & 3];
        const size_t row = hoff + (size_t)(q0 + q) * 64;
        if (dc < 64) out[row + dc] = val;
        else out[OUT2_OFF + row + (dc - 64)] = val;
      }
    }
  }
}

// =====================  fallback (round-1, verified) for small ws  =====================
__device__ __forceinline__ int swz(int r, int c, int cols) {
  return r * cols + (((c >> 3) ^ (r & 7)) << 3) + (c & 7);
}

__global__ __launch_bounds__(256, 2) void fattn_fb_kernel(
    const float* __restrict__ Qx, const float* __restrict__ Kx,
    const float* __restrict__ Vx, const float* __restrict__ Qy,
    const float* __restrict__ Ky, const float* __restrict__ Vy,
    float* __restrict__ out) {
  __shared__ unsigned short Kl[KB * DC];
  __shared__ unsigned short Vl[DC * KB];
  __shared__ unsigned short Pl[4 * 16 * KB];

  const int tid = threadIdx.x;
  const int w = tid >> 6, l = tid & 63, l15 = l & 15, l4 = l >> 4;
  const int braw = blockIdx.x;
  const int bid = (braw & 7) * 128 + (braw >> 3);
  const int bh = bid >> 4, qt = bid & 15, q0 = qt * 64;
  const size_t hoff = (size_t)bh * S_LEN * D_HEAD;
  const float* qx = Qx + hoff; const float* qy = Qy + hoff;
  const float* kx = Kx + hoff; const float* ky = Ky + hoff;
  const float* vx = Vx + hoff; const float* vy = Vy + hoff;

  bf16x8 qf[4];
  {
    const int qrow = q0 + 16 * w + l15;
#pragma unroll
    for (int db = 0; db < 4; ++db) {
      const int dcomb = 32 * db + 8 * l4;
      const float* src = (dcomb < 64) ? (qx + qrow * D_HEAD + dcomb)
                                      : (qy + qrow * D_HEAD + (dcomb - 64));
      float4 a = *(const float4*)src;
      float4 c = *(const float4*)(src + 4);
      union { unsigned short s[8]; bf16x8 v; } u;
      u.s[0] = bf16u(a.x * SCALE_LOG2E); u.s[1] = bf16u(a.y * SCALE_LOG2E);
      u.s[2] = bf16u(a.z * SCALE_LOG2E); u.s[3] = bf16u(a.w * SCALE_LOG2E);
      u.s[4] = bf16u(c.x * SCALE_LOG2E); u.s[5] = bf16u(c.y * SCALE_LOG2E);
      u.s[6] = bf16u(c.z * SCALE_LOG2E); u.s[7] = bf16u(c.w * SCALE_LOG2E);
      qf[db] = u.v;
    }
  }

  f32x4 o[8];
#pragma unroll
  for (int i = 0; i < 8; ++i) o[i] = f32x4{0.f, 0.f, 0.f, 0.f};
  float m[4] = {-__builtin_inff(), -__builtin_inff(), -__builtin_inff(), -__builtin_inff()};
  float lsum[4] = {0.f, 0.f, 0.f, 0.f};

  for (int k0 = 0; k0 < S_LEN; k0 += KB) {
    __syncthreads();
#pragma unroll
    for (int jj = 0; jj < 8; ++jj) {
      const int c = tid + 256 * jj;
      const int key = c >> 5, dc = c & 31;
      const float* src = (dc < 16) ? (kx + (size_t)(k0 + key) * D_HEAD + dc * 4)
                                   : (ky + (size_t)(k0 + key) * D_HEAD + (dc - 16) * 4);
      float4 v = *(const float4*)src;
      ushort4 pkk;
      pkk.x = bf16u(v.x); pkk.y = bf16u(v.y); pkk.z = bf16u(v.z); pkk.w = bf16u(v.w);
      *(ushort4*)&Kl[swz(key, dc * 4, DC)] = pkk;
    }
#pragma unroll
    for (int jj = 0; jj < 8; ++jj) {
      const int u = w + 4 * jj, st = u >> 4, kbb = u & 15;
      const int e = l & 3, a = l >> 2;
      const float* vsrc = st ? vy : vx;
      float4 val = *(const float4*)(vsrc + (size_t)(k0 + kbb * 4 + e) * D_HEAD + a * 4);
      float t0[4] = {val.x, val.y, val.z, val.w};
      float t1[4], t2[4];
#pragma unroll
      for (int mi = 0; mi < 4; ++mi) {
        float other = __shfl_xor(t0[mi ^ 1], 1);
        t1[mi] = ((mi & 1) == (e & 1)) ? t0[mi] : other;
      }
#pragma unroll
      for (int mi = 0; mi < 4; ++mi) {
        float other = __shfl_xor(t1[mi ^ 2], 2);
        t2[mi] = ((mi & 2) == (e & 2)) ? t1[mi] : other;
      }
      const int dcomb = st * 64 + a * 4 + e;
      ushort4 pkk;
      pkk.x = bf16u(t2[0]); pkk.y = bf16u(t2[1]); pkk.z = bf16u(t2[2]); pkk.w = bf16u(t2[3]);
      *(ushort4*)&Vl[swz(dcomb, kbb * 4, KB)] = pkk;
    }
    __syncthreads();

    f32x4 s[4];
#pragma unroll
    for (int kt = 0; kt < 4; ++kt) {
      f32x4 acc = f32x4{0.f, 0.f, 0.f, 0.f};
#pragma unroll
      for (int db = 0; db < 4; ++db) {
        bf16x8 bk = *(const bf16x8*)&Kl[swz(16 * kt + l15, 32 * db + 8 * l4, DC)];
        acc = __builtin_amdgcn_mfma_f32_16x16x32_bf16(qf[db], bk, acc, 0, 0, 0);
      }
      s[kt] = acc;
    }

    unsigned short pout[4][4];
    float scl[4];
#pragma unroll
    for (int r = 0; r < 4; ++r) {
      float mxx = fmaxf(fmaxf(s[0][r], s[1][r]), fmaxf(s[2][r], s[3][r]));
      mxx = fmaxf(mxx, __shfl_xor(mxx, 1));
      mxx = fmaxf(mxx, __shfl_xor(mxx, 2));
      mxx = fmaxf(mxx, __shfl_xor(mxx, 4));
      mxx = fmaxf(mxx, __shfl_xor(mxx, 8));
      const float mnew = fmaxf(m[r], mxx);
      const float sc = exp2f(m[r] - mnew);
      m[r] = mnew; scl[r] = sc; lsum[r] *= sc;
      float rsum = 0.f;
#pragma unroll
      for (int kt = 0; kt < 4; ++kt) {
        float p = exp2f(s[kt][r] - mnew);
        rsum += p;
        pout[kt][r] = bf16u(p);
      }
      rsum += __shfl_xor(rsum, 1);
      rsum += __shfl_xor(rsum, 2);
      rsum += __shfl_xor(rsum, 4);
      rsum += __shfl_xor(rsum, 8);
      lsum[r] += rsum;
    }
#pragma unroll
    for (int dt = 0; dt < 8; ++dt)
#pragma unroll
      for (int r = 0; r < 4; ++r) o[dt][r] *= scl[r];

    unsigned short* pw = &Pl[w * 16 * KB];
#pragma unroll
    for (int kt = 0; kt < 4; ++kt)
#pragma unroll
      for (int r = 0; r < 4; ++r)
        pw[swz(4 * l4 + r, 16 * kt + l15, KB)] = pout[kt][r];

#pragma unroll
    for (int sl = 0; sl < 2; ++sl) {
      bf16x8 pf = *(const bf16x8*)&pw[swz(l15, 32 * sl + 8 * l4, KB)];
#pragma unroll
      for (int dt = 0; dt < 8; ++dt) {
        bf16x8 vf = *(const bf16x8*)&Vl[swz(16 * dt + l15, 32 * sl + 8 * l4, KB)];
        o[dt] = __builtin_amdgcn_mfma_f32_16x16x32_bf16(pf, vf, o[dt], 0, 0, 0);
      }
    }
  }

#pragma unroll
  for (int r = 0; r < 4; ++r) {
    const float inv = 1.0f / lsum[r];
    const int qrow = q0 + 16 * w + 4 * l4 + r;
#pragma unroll
    for (int dt = 0; dt < 8; ++dt) {
      const int dcomb = 16 * dt + l15;
      const float val = o[dt][r] * inv;
      if (dcomb < 64) out[hoff + (size_t)qrow * D_HEAD + dcomb] = val;
      else out[OUT2_OFF + hoff + (size_t)qrow * D_HEAD + (dcomb - 64)] = val;
    }
  }
}

extern "C" void kernel_launch(void* const* d_in, const int* in_sizes, int n_in,
                              void* d_out, int out_size, void* d_ws, size_t ws_size,
                              hipStream_t stream) {
  const float* Qx = (const float*)d_in[0];
  const float* Kx = (const float*)d_in[1];
  const float* Vx = (const float*)d_in[2];
  const float* Qy = (const float*)d_in[3];
  const float* Ky = (const float*)d_in[4];
  const float* Vy = (const float*)d_in[5];
  float* out = (float*)d_out;

  if (ws_size >= 2 * KWS) {
    unsigned char* kbp = (unsigned char*)d_ws;
    unsigned char* vbp = kbp + KWS;
    prepass_kernel<<<8192, 256, 0, stream>>>(Kx, Ky, Vx, Vy, kbp, vbp);
    fattn2_kernel<<<512, 256, 0, stream>>>(Qx, Qy, kbp, vbp, out);
  } else {
    fattn_fb_kernel<<<1024, 256, 0, stream>>>(Qx, Kx, Vx, Qy, Ky, Vy, out);
  }
}